// Round 7
// baseline (169.138 us; speedup 1.0000x reference)
//
#include <hip/hip_runtime.h>
#include <math.h>

#define NI 256
#define NJ 256
#define NK 1024
#define JPW 8              // j-rows per wave
#define WPB 4              // waves per block
#define JPB (JPW * WPB)    // 32 j-rows per block
#define PAD 16
#define LROW (PAD + NK + PAD)   // 1056 floats per array

typedef float float4v __attribute__((ext_vector_type(4)));

__device__ __forceinline__ float finalize(float n, float d) {
    // semblance <= 1 mathematically (Cauchy-Schwarz) -> no overflow possible;
    // only 0/0 -> nan -> 1.0 per nan_to_num. rcp is ~1 ulp, threshold 1.56e-2.
    float r = n * __builtin_amdgcn_rcpf(d);
    if (!(r == r)) r = 1.0f;
    return r;
}

// 20-wide sliding window over a lane's 16 outputs.
// Own values U0..U3 (floats k0..k0+15), halos L0..L2 (k0-12..k0-1),
// R0,R1 (k0+16..k0+23), RX (k0+24). Window for output e: [k0-10+e, k0+9+e].
#define KWIN(P, U0, U1, U2, U3, L0, L1, L2, R0, R1, RX)                          \
    const float4v P##a = (L1) + (L2) + (U0) + (U1);                              \
    const float P##w0  = P##a[0] + P##a[1] + P##a[2] + P##a[3]                   \
                       + (L0)[2] + (L0)[3] + (U2)[0] + (U2)[1];                  \
    const float P##w1  = P##w0  + (U2)[2] - (L0)[2];                             \
    const float P##w2  = P##w1  + (U2)[3] - (L0)[3];                             \
    const float P##w3  = P##w2  + (U3)[0] - (L1)[0];                             \
    const float P##w4  = P##w3  + (U3)[1] - (L1)[1];                             \
    const float P##w5  = P##w4  + (U3)[2] - (L1)[2];                             \
    const float P##w6  = P##w5  + (U3)[3] - (L1)[3];                             \
    const float P##w7  = P##w6  + (R0)[0] - (L2)[0];                             \
    const float P##w8  = P##w7  + (R0)[1] - (L2)[1];                             \
    const float P##w9  = P##w8  + (R0)[2] - (L2)[2];                             \
    const float P##w10 = P##w9  + (R0)[3] - (L2)[3];                             \
    const float P##w11 = P##w10 + (R1)[0] - (U0)[0];                             \
    const float P##w12 = P##w11 + (R1)[1] - (U0)[1];                             \
    const float P##w13 = P##w12 + (R1)[2] - (U0)[2];                             \
    const float P##w14 = P##w13 + (R1)[3] - (U0)[3];                             \
    const float P##w15 = P##w14 + (RX)    - (U1)[0];

__global__ __launch_bounds__(256)
void semblance_kernel(const float* __restrict__ x, float* __restrict__ out) {
    // wave-private regions: no cross-wave sharing, zero block barriers
    __shared__ __align__(16) float lds[WPB][2][LROW];

    const int tid  = threadIdx.x;
    const int lane = tid & 63;
    const int wave = tid >> 6;
    const int i    = blockIdx.y;
    const int jW   = blockIdx.x * JPB + wave * JPW;
    const int k0   = lane * 16;        // this lane's 16 consecutive k

    float* Pn = &lds[wave][0][0];
    float* Pd = &lds[wave][1][0];

    // zero the 16-float pads on both sides of both arrays, once (16 quads)
    if (lane < 16) {
        const int q    = lane & 3;
        const int side = (lane >> 2) & 1;
        float* P = (lane >> 3) ? Pd : Pn;
        *(float4v*)(P + (side ? (PAD + NK) : 0) + 4 * q) = (float4v)0.f;
    }

    const float* xi = x + (size_t)i * NJ * NK + k0;

    // running j-window sums over rows jW-2..jW+2: s = sum x, t = sum x^2
    float4v s0 = (float4v)0.f, s1 = s0, s2 = s0, s3 = s0;
    float4v t0 = s0, t1 = s0, t2 = s0, t3 = s0;
    #pragma unroll
    for (int dj = -2; dj <= 2; ++dj) {
        const int r = jW + dj;
        if (r >= 0 && r < NJ) {
            const float* xr = xi + (size_t)r * NK;
            float4v a0 = *(const float4v*)(xr + 0);
            float4v a1 = *(const float4v*)(xr + 4);
            float4v a2 = *(const float4v*)(xr + 8);
            float4v a3 = *(const float4v*)(xr + 12);
            s0 += a0; s1 += a1; s2 += a2; s3 += a3;
            t0 += a0 * a0; t1 += a1 * a1; t2 += a2 * a2; t3 += a3 * a3;
        }
    }

    #pragma unroll 1
    for (int jj = 0; jj < JPW; ++jj) {
        const int j = jW + jj;

        // issue the slide rows early (j+3 in, j-2 out); wave-uniform branches
        float4v n0 = (float4v)0.f, n1 = n0, n2 = n0, n3 = n0;
        float4v m0 = n0, m1 = n0, m2 = n0, m3 = n0;
        if (j + 3 < NJ) {
            const float* xr = xi + (size_t)(j + 3) * NK;
            n0 = *(const float4v*)(xr + 0);
            n1 = *(const float4v*)(xr + 4);
            n2 = *(const float4v*)(xr + 8);
            n3 = *(const float4v*)(xr + 12);
        }
        if (j - 2 >= 0) {
            const float* xr = xi + (size_t)(j - 2) * NK;
            m0 = *(const float4v*)(xr + 0);
            m1 = *(const float4v*)(xr + 4);
            m2 = *(const float4v*)(xr + 8);
            m3 = *(const float4v*)(xr + 12);
        }

        // own window values for row j (copies — s,t update below reuses s,t)
        const float4v un0 = s0 * s0, un1 = s1 * s1, un2 = s2 * s2, un3 = s3 * s3;
        const float4v ud0 = t0, ud1 = t1, ud2 = t2, ud3 = t3;

        // publish s^2 and t to the wave-private LDS row
        *(float4v*)(Pn + PAD + k0 + 0)  = un0;
        *(float4v*)(Pn + PAD + k0 + 4)  = un1;
        *(float4v*)(Pn + PAD + k0 + 8)  = un2;
        *(float4v*)(Pn + PAD + k0 + 12) = un3;
        *(float4v*)(Pd + PAD + k0 + 0)  = ud0;
        *(float4v*)(Pd + PAD + k0 + 4)  = ud1;
        *(float4v*)(Pd + PAD + k0 + 8)  = ud2;
        *(float4v*)(Pd + PAD + k0 + 12) = ud3;

        // slide the running sums now (frees n,m before the window phase)
        s0 += n0 - m0; s1 += n1 - m1; s2 += n2 - m2; s3 += n3 - m3;
        t0 += n0 * n0 - m0 * m0; t1 += n1 * n1 - m1 * m1;
        t2 += n2 * n2 - m2 * m2; t3 += n3 * n3 - m3 * m3;

        // wave-internal write->read ordering (DS pipe in-order per wave)
        __builtin_amdgcn_wave_barrier();
        asm volatile("" ::: "memory");

        // halo reads: only +/-12 floats from neighbor lanes (pads give zeros)
        const float* Bn = Pn + PAD + k0;
        const float* Bd = Pd + PAD + k0;
        const float4v ln0 = *(const float4v*)(Bn - 12);
        const float4v ln1 = *(const float4v*)(Bn - 8);
        const float4v ln2 = *(const float4v*)(Bn - 4);
        const float4v rn0 = *(const float4v*)(Bn + 16);
        const float4v rn1 = *(const float4v*)(Bn + 20);
        const float   rnx = Bn[24];
        const float4v ld0 = *(const float4v*)(Bd - 12);
        const float4v ld1 = *(const float4v*)(Bd - 8);
        const float4v ld2 = *(const float4v*)(Bd - 4);
        const float4v rd0 = *(const float4v*)(Bd + 16);
        const float4v rd1 = *(const float4v*)(Bd + 20);
        const float   rdx = Bd[24];

        KWIN(n, un0, un1, un2, un3, ln0, ln1, ln2, rn0, rn1, rnx)
        KWIN(d, ud0, ud1, ud2, ud3, ld0, ld1, ld2, rd0, rd1, rdx)

        const int jlo = (j - 2 < 0) ? 0 : j - 2;
        const int jhi = (j + 2 > NJ - 1) ? NJ - 1 : j + 2;
        const float norm = (float)(jhi - jlo + 1);

        float* op = out + ((size_t)i * NJ + j) * NK + k0;
        float4v o;
        o[0] = finalize(nw0,  dw0  * norm); o[1] = finalize(nw1,  dw1  * norm);
        o[2] = finalize(nw2,  dw2  * norm); o[3] = finalize(nw3,  dw3  * norm);
        *(float4v*)(op + 0) = o;
        o[0] = finalize(nw4,  dw4  * norm); o[1] = finalize(nw5,  dw5  * norm);
        o[2] = finalize(nw6,  dw6  * norm); o[3] = finalize(nw7,  dw7  * norm);
        *(float4v*)(op + 4) = o;
        o[0] = finalize(nw8,  dw8  * norm); o[1] = finalize(nw9,  dw9  * norm);
        o[2] = finalize(nw10, dw10 * norm); o[3] = finalize(nw11, dw11 * norm);
        *(float4v*)(op + 8) = o;
        o[0] = finalize(nw12, dw12 * norm); o[1] = finalize(nw13, dw13 * norm);
        o[2] = finalize(nw14, dw14 * norm); o[3] = finalize(nw15, dw15 * norm);
        *(float4v*)(op + 12) = o;

        // order this iteration's LDS reads before next iteration's writes
        __builtin_amdgcn_wave_barrier();
        asm volatile("" ::: "memory");
    }
}

extern "C" void kernel_launch(void* const* d_in, const int* in_sizes, int n_in,
                              void* d_out, int out_size, void* d_ws, size_t ws_size,
                              hipStream_t stream) {
    const float* x = (const float*)d_in[0];
    float* out = (float*)d_out;
    dim3 grid(NJ / JPB, NI);   // (8, 256) = 2048 blocks, 4 independent waves each
    semblance_kernel<<<grid, 256, 0, stream>>>(x, out);
}

// Round 8
// 123.909 us; speedup vs baseline: 1.3650x; 1.3650x over previous
//
#include <hip/hip_runtime.h>
#include <math.h>

#define NI 256
#define NJ 256
#define NK 1024
#define JCHUNK 32
#define HALO 16
#define LROW (HALO + NK + HALO)   // 1056 floats

typedef float float4v __attribute__((ext_vector_type(4)));

__device__ __forceinline__ float finalize(float n, float d) {
    // semblance <= 1 (Cauchy-Schwarz): no overflow. d==0 implies n==0 ->
    // 0*inf = nan -> 1.0 (matches nan_to_num). rcp ~1 ulp vs 1.56e-2 threshold.
    float r = n * __builtin_amdgcn_rcpf(d);
    if (!(r == r)) r = 1.0f;
    return r;
}

// Sliding 20-window sums along k, all-aligned b128 reads (conflict-free, R5/R6).
// Quads Q0..Q6 cover floats [base-12, base+15].
//   w0 = f[base-10 .. base+9]; w_{e+1} = w_e + f[base+10+e] - f[base-10+e]
__device__ __forceinline__ void kwindow(const float* __restrict__ row, int base,
                                        float& w0, float& w1, float& w2, float& w3) {
    const float4v* p = (const float4v*)(row + HALO + base - 12);
    float4v q0 = p[0], q1 = p[1], q2 = p[2], q3 = p[3], q4 = p[4], q5 = p[5], q6 = p[6];
    float4v midv = (q1 + q2) + (q3 + q4);
    float mid = (midv[0] + midv[1]) + (midv[2] + midv[3]);
    w0 = q0[2] + q0[3] + mid + q5[0] + q5[1];
    w1 = w0 + q5[2] - q0[2];
    w2 = w1 + q5[3] - q0[3];
    w3 = w2 + q6[0] - q1[0];
}

__global__ __launch_bounds__(256)
void semblance_kernel(const float* __restrict__ x, float* __restrict__ out) {
    // block-shared, double-buffered s1^2 and sum(x^2) rows, static zero pads
    __shared__ __align__(16) float s_num[2][LROW];
    __shared__ __align__(16) float s_den[2][LROW];

    const int tid  = threadIdx.x;
    const int i    = blockIdx.y;
    const int j0   = blockIdx.x * JCHUNK;
    const int base = tid * 4;

    // zero the pads ONCE — x is zero outside [0,NK)
    if (tid < HALO) {
        s_num[0][tid] = 0.f; s_den[0][tid] = 0.f;
        s_num[1][tid] = 0.f; s_den[1][tid] = 0.f;
        s_num[0][HALO + NK + tid] = 0.f; s_den[0][HALO + NK + tid] = 0.f;
        s_num[1][HALO + NK + tid] = 0.f; s_den[1][HALO + NK + tid] = 0.f;
    }

    const float* xk = x + (size_t)i * NJ * NK + base;

    // running j-window sums over rows j0-2..j0+2
    float4v s = (float4v)0.f, t = (float4v)0.f;
    #pragma unroll
    for (int dj = -2; dj <= 2; ++dj) {
        const int r = j0 + dj;
        if (r >= 0 && r < NJ) {
            float4v v = *(const float4v*)(xk + (size_t)r * NK);
            s += v;
            t += v * v;
        }
    }

    #pragma unroll 2
    for (int jj = 0; jj < JCHUNK; ++jj) {
        const int j = j0 + jj;
        const int b = jj & 1;

        // publish row j's window values (pre-update s,t)
        float4v un = s * s;
        *(float4v*)(&s_num[b][HALO + base]) = un;
        *(float4v*)(&s_den[b][HALO + base]) = t;

        // issue slide rows early: incoming j+3 (HBM/L2), outgoing j-2 (L2-hot)
        float4v n = (float4v)0.f, m = (float4v)0.f;
        if (j + 3 < NJ) n = *(const float4v*)(xk + (size_t)(j + 3) * NK);
        if (j - 2 >= 0) m = *(const float4v*)(xk + (size_t)(j - 2) * NK);

        __syncthreads();

        float wn0, wn1, wn2, wn3, wd0, wd1, wd2, wd3;
        kwindow(s_num[b], base, wn0, wn1, wn2, wn3);
        kwindow(s_den[b], base, wd0, wd1, wd2, wd3);

        const int jlo = (j - 2 < 0) ? 0 : j - 2;
        const int jhi = (j + 2 > NJ - 1) ? NJ - 1 : j + 2;
        const float norm = (float)(jhi - jlo + 1);

        float4v o;
        o[0] = finalize(wn0, wd0 * norm);
        o[1] = finalize(wn1, wd1 * norm);
        o[2] = finalize(wn2, wd2 * norm);
        o[3] = finalize(wn3, wd3 * norm);
        // non-temporal store: keep the output stream out of L3 so x stays resident
        __builtin_nontemporal_store(o, (float4v*)(out + ((size_t)i * NJ + j) * NK + base));

        // slide the running sums for the next row
        s += n - m;
        t += n * n - m * m;
        // single barrier per iteration: next iter writes the OTHER buffer;
        // its barrier orders those writes after all reads of this buffer
    }
}

extern "C" void kernel_launch(void* const* d_in, const int* in_sizes, int n_in,
                              void* d_out, int out_size, void* d_ws, size_t ws_size,
                              hipStream_t stream) {
    const float* x = (const float*)d_in[0];
    float* out = (float*)d_out;
    dim3 grid(NJ / JCHUNK, NI);   // (8, 256) = 2048 blocks
    semblance_kernel<<<grid, 256, 0, stream>>>(x, out);
}

// Round 9
// 96.535 us; speedup vs baseline: 1.7521x; 1.2836x over previous
//
#include <hip/hip_runtime.h>
#include <math.h>

#define NI 256
#define NJ 256
#define NK 1024
#define JCHUNK 32
#define HALO 16
#define LROW (HALO + NK + HALO)   // 1056 floats

typedef float float4v __attribute__((ext_vector_type(4)));

__device__ __forceinline__ float finalize(float n, float d) {
    // semblance <= 1 (Cauchy-Schwarz): no overflow. d==0 implies n==0 ->
    // 0*inf = nan -> 1.0 (matches nan_to_num). rcp ~1 ulp vs 1.56e-2 threshold.
    float r = n * __builtin_amdgcn_rcpf(d);
    if (!(r == r)) r = 1.0f;
    return r;
}

// Sliding 20-window sums along k, all-aligned b128 reads (conflict-free).
// Quads Q0..Q6 cover floats [base-12, base+15].
//   w0 = f[base-10 .. base+9]; w_{e+1} = w_e + f[base+10+e] - f[base-10+e]
__device__ __forceinline__ void kwindow(const float* __restrict__ row, int base,
                                        float& w0, float& w1, float& w2, float& w3) {
    const float4v* p = (const float4v*)(row + HALO + base - 12);
    float4v q0 = p[0], q1 = p[1], q2 = p[2], q3 = p[3], q4 = p[4], q5 = p[5], q6 = p[6];
    float4v midv = (q1 + q2) + (q3 + q4);
    float mid = (midv[0] + midv[1]) + (midv[2] + midv[3]);
    w0 = q0[2] + q0[3] + mid + q5[0] + q5[1];
    w1 = w0 + q5[2] - q0[2];
    w2 = w1 + q5[3] - q0[3];
    w3 = w2 + q6[0] - q1[0];
}

__global__ __launch_bounds__(256)
void semblance_kernel(const float* __restrict__ x, float* __restrict__ out) {
    // block-shared, double-buffered s1^2 and sum(x^2) rows, static zero pads
    __shared__ __align__(16) float s_num[2][LROW];
    __shared__ __align__(16) float s_den[2][LROW];

    const int tid  = threadIdx.x;
    const int i    = blockIdx.y;
    const int j0   = blockIdx.x * JCHUNK;
    const int base = tid * 4;

    // zero the pads ONCE — x is zero outside [0,NK)
    if (tid < HALO) {
        s_num[0][tid] = 0.f; s_den[0][tid] = 0.f;
        s_num[1][tid] = 0.f; s_den[1][tid] = 0.f;
        s_num[0][HALO + NK + tid] = 0.f; s_den[0][HALO + NK + tid] = 0.f;
        s_num[1][HALO + NK + tid] = 0.f; s_den[1][HALO + NK + tid] = 0.f;
    }

    const float* xk = x + (size_t)i * NJ * NK + base;

    // register ring r0..r4 = rows j0-2..j0+2 (zero outside), plus running sums
    float4v r0, r1, r2, r3, r4;
    r0 = (j0 - 2 >= 0) ? *(const float4v*)(xk + (size_t)(j0 - 2) * NK) : (float4v)0.f;
    r1 = (j0 - 1 >= 0) ? *(const float4v*)(xk + (size_t)(j0 - 1) * NK) : (float4v)0.f;
    r2 = *(const float4v*)(xk + (size_t)j0 * NK);
    r3 = (j0 + 1 < NJ) ? *(const float4v*)(xk + (size_t)(j0 + 1) * NK) : (float4v)0.f;
    r4 = (j0 + 2 < NJ) ? *(const float4v*)(xk + (size_t)(j0 + 2) * NK) : (float4v)0.f;
    float4v s = (r0 + r1) + (r2 + r3) + r4;
    float4v t = (r0 * r0 + r1 * r1) + (r2 * r2 + r3 * r3) + r4 * r4;

    #pragma unroll 2
    for (int jj = 0; jj < JCHUNK; ++jj) {
        const int j = j0 + jj;
        const int b = jj & 1;

        // publish row j's window values
        float4v un = s * s;
        *(float4v*)(&s_num[b][HALO + base]) = un;
        *(float4v*)(&s_den[b][HALO + base]) = t;

        // prefetch the single incoming row (j+3); outgoing row comes from the ring
        float4v n = (float4v)0.f;
        if (j + 3 < NJ) n = *(const float4v*)(xk + (size_t)(j + 3) * NK);

        __syncthreads();

        float wn0, wn1, wn2, wn3, wd0, wd1, wd2, wd3;
        kwindow(s_num[b], base, wn0, wn1, wn2, wn3);
        kwindow(s_den[b], base, wd0, wd1, wd2, wd3);

        const int jlo = (j - 2 < 0) ? 0 : j - 2;
        const int jhi = (j + 2 > NJ - 1) ? NJ - 1 : j + 2;
        const float norm = (float)(jhi - jlo + 1);

        float4v o;
        o[0] = finalize(wn0, wd0 * norm);
        o[1] = finalize(wn1, wd1 * norm);
        o[2] = finalize(wn2, wd2 * norm);
        o[3] = finalize(wn3, wd3 * norm);
        // non-temporal store: keep the 268 MB output stream out of L3 so x stays resident
        __builtin_nontemporal_store(o, (float4v*)(out + ((size_t)i * NJ + j) * NK + base));

        // slide running sums from the ring (no j-2 reload)
        s += n - r0;
        t += n * n - r0 * r0;
        r0 = r1; r1 = r2; r2 = r3; r3 = r4; r4 = n;
        // single barrier per iteration: next iter writes the OTHER buffer;
        // its barrier orders those writes after all reads of this buffer
    }
}

extern "C" void kernel_launch(void* const* d_in, const int* in_sizes, int n_in,
                              void* d_out, int out_size, void* d_ws, size_t ws_size,
                              hipStream_t stream) {
    const float* x = (const float*)d_in[0];
    float* out = (float*)d_out;
    dim3 grid(NJ / JCHUNK, NI);   // (8, 256) = 2048 blocks
    semblance_kernel<<<grid, 256, 0, stream>>>(x, out);
}

// Round 10
// 92.562 us; speedup vs baseline: 1.8273x; 1.0429x over previous
//
#include <hip/hip_runtime.h>
#include <math.h>

#define NI 256
#define NJ 256
#define NK 1024
#define JCHUNK 32
#define WPB 4
#define KSEG 256
#define WREG 288   // 16 left pad/halo + 256 own + 16 right halo (floats)

typedef float float4v __attribute__((ext_vector_type(4)));

__device__ __forceinline__ float finalize(float n, float d) {
    // semblance <= 1 (Cauchy-Schwarz): no overflow. 0/0 -> 0*inf = nan -> 1.0.
    float r = n * __builtin_amdgcn_rcpf(d);
    if (!(r == r)) r = 1.0f;
    return r;
}

// 20-wide sliding k-window, all-aligned b128 reads (conflict-free).
// p0 points at float idx (own_base - 12) of the logical row.
__device__ __forceinline__ void kwindow(const float* __restrict__ p0,
                                        float& w0, float& w1, float& w2, float& w3) {
    const float4v* p = (const float4v*)p0;
    float4v q0 = p[0], q1 = p[1], q2 = p[2], q3 = p[3], q4 = p[4], q5 = p[5], q6 = p[6];
    float4v midv = (q1 + q2) + (q3 + q4);
    float mid = (midv[0] + midv[1]) + (midv[2] + midv[3]);
    w0 = q0[2] + q0[3] + mid + q5[0] + q5[1];
    w1 = w0 + q5[2] - q0[2];
    w2 = w1 + q5[3] - q0[3];
    w3 = w2 + q6[0] - q1[0];
}

__global__ __launch_bounds__(256)
void semblance_kernel(const float* __restrict__ x, float* __restrict__ out) {
    // wave-private regions, single-buffered: zero s_barriers in the kernel.
    // Region float idx g-k0s+16 holds global k = g: [0..15]=left halo,
    // [16..271]=own segment, [272..287]=right halo.
    __shared__ __align__(16) float lds[WPB][2][WREG];

    const int tid  = threadIdx.x;
    const int lane = tid & 63;
    const int wave = tid >> 6;
    const int i    = blockIdx.y;
    const int j0   = blockIdx.x * JCHUNK;
    const int k0s  = wave * KSEG;
    const int kb   = k0s + 4 * lane;       // this lane's first global k

    float* Pn = &lds[wave][0][0];
    float* Pd = &lds[wave][1][0];

    // halo duty: lanes 0-2 -> left quads (idx 4,8,12), lanes 3-5 -> right (272,276,280)
    const bool hal  = (lane < 6);
    const int  hidx = (lane < 3) ? (4 + 4 * lane) : (272 + 4 * (lane - 3));
    const int  hk   = k0s + hidx - 16;     // global k of halo quad
    const bool hok  = hal && (hk >= 0) && (hk < NK);

    // zero halo quads once (out-of-range ones stay zero forever)
    if (hal) {
        *(float4v*)(Pn + hidx) = (float4v)0.f;
        *(float4v*)(Pd + hidx) = (float4v)0.f;
    }

    const float* xi = x + (size_t)i * NJ * NK;
    const float* xk = xi + kb;
    const float* xh = xi + hk;             // only dereferenced when hok

    // main running sums + ring over rows j0-2..j0+2
    float4v r0, r1, r2, r3, r4;
    r0 = (j0 - 2 >= 0) ? *(const float4v*)(xk + (size_t)(j0 - 2) * NK) : (float4v)0.f;
    r1 = (j0 - 1 >= 0) ? *(const float4v*)(xk + (size_t)(j0 - 1) * NK) : (float4v)0.f;
    r2 = *(const float4v*)(xk + (size_t)j0 * NK);
    r3 = (j0 + 1 < NJ) ? *(const float4v*)(xk + (size_t)(j0 + 1) * NK) : (float4v)0.f;
    r4 = (j0 + 2 < NJ) ? *(const float4v*)(xk + (size_t)(j0 + 2) * NK) : (float4v)0.f;
    float4v s = (r0 + r1) + (r2 + r3) + r4;
    float4v t = (r0 * r0 + r1 * r1) + (r2 * r2 + r3 * r3) + r4 * r4;

    // halo running sums (ring-less: outgoing row is reloaded, L1-hot)
    float4v hs = (float4v)0.f, ht = (float4v)0.f;
    if (hok) {
        #pragma unroll
        for (int dj = -2; dj <= 2; ++dj) {
            const int r = j0 + dj;
            if (r >= 0 && r < NJ) {
                float4v v = *(const float4v*)(xh + (size_t)r * NK);
                hs += v; ht += v * v;
            }
        }
    }

    #pragma unroll 2
    for (int jj = 0; jj < JCHUNK; ++jj) {
        const int j = j0 + jj;

        // publish row j (own quad + halo quad)
        *(float4v*)(Pn + 16 + 4 * lane) = s * s;
        *(float4v*)(Pd + 16 + 4 * lane) = t;
        if (hok) {
            *(float4v*)(Pn + hidx) = hs * hs;
            *(float4v*)(Pd + hidx) = ht;
        }

        // issue next-row loads now; consumed only at iteration END -> the whole
        // LDS-read + compute + store phase hides their latency (no barrier drain)
        float4v n = (float4v)0.f, hn = (float4v)0.f, hm = (float4v)0.f;
        if (j + 3 < NJ) n = *(const float4v*)(xk + (size_t)(j + 3) * NK);
        if (hok) {
            if (j + 3 < NJ) hn = *(const float4v*)(xh + (size_t)(j + 3) * NK);
            if (j - 2 >= 0) hm = *(const float4v*)(xh + (size_t)(j - 2) * NK);
        }

        // wave-internal write->read ordering (DS pipe in-order per wave; R4 precedent)
        __builtin_amdgcn_wave_barrier();
        asm volatile("" ::: "memory");

        float wn0, wn1, wn2, wn3, wd0, wd1, wd2, wd3;
        kwindow(Pn + 4 + 4 * lane, wn0, wn1, wn2, wn3);
        kwindow(Pd + 4 + 4 * lane, wd0, wd1, wd2, wd3);

        const int jlo = (j - 2 < 0) ? 0 : j - 2;
        const int jhi = (j + 2 > NJ - 1) ? NJ - 1 : j + 2;
        const float norm = (float)(jhi - jlo + 1);

        float4v o;
        o[0] = finalize(wn0, wd0 * norm);
        o[1] = finalize(wn1, wd1 * norm);
        o[2] = finalize(wn2, wd2 * norm);
        o[3] = finalize(wn3, wd3 * norm);
        __builtin_nontemporal_store(o, (float4v*)(out + ((size_t)i * NJ + j) * NK + kb));

        // slide running sums (vmcnt wait lands here, far from the issue point)
        s += n - r0;
        t += n * n - r0 * r0;
        r0 = r1; r1 = r2; r2 = r3; r3 = r4; r4 = n;
        if (hok) { hs += hn - hm; ht += hn * hn - hm * hm; }

        // order this iteration's LDS reads before next iteration's writes
        __builtin_amdgcn_wave_barrier();
        asm volatile("" ::: "memory");
    }
}

extern "C" void kernel_launch(void* const* d_in, const int* in_sizes, int n_in,
                              void* d_out, int out_size, void* d_ws, size_t ws_size,
                              hipStream_t stream) {
    const float* x = (const float*)d_in[0];
    float* out = (float*)d_out;
    dim3 grid(NJ / JCHUNK, NI);   // (8, 256) = 2048 blocks, 4 independent waves each
    semblance_kernel<<<grid, 256, 0, stream>>>(x, out);
}